// Round 11
// baseline (186.358 us; speedup 1.0000x reference)
//
#include <hip/hip_runtime.h>

#define W 126
#define NPIX 15876      // 126*126
#define NB 16
#define NCH 8
#define NCLS 100

#define CC 10           // classes per chunk
#define NBLK_A 840      // 3360 waves: cy(10) x b(16) x m(7) x kg(3)

// ws layout (floats): MT at 256, barrier cnt at 3072, partials at 4096..
#define WS_MT_OFF 256
#define WS_CNT_OFF 3072
#define WS_PART_OFF 4096

// ---------------------------------------------------------------------------
// Kernel A: binned contraction of logits + (last-block) final reduce + build.
// Wave = (class-chunk cy, batch b, row-residue m, pair-group kg): processes
// 3 row-pairs that all satisfy y%7 == m (pair = (4m)%7 + 7k), 10 classes,
// 30 float4 loads deep. Lane-fixed slots -> register accumulation (R6 body).
// After writing its 196-float partial, each block takes a ticket; the LAST
// block (ticket 839) reduces all partials (coalesced, 4-way ILP) and runs
// the gaussian build -> MT. Eliminates 2 dispatches + 2 launch gaps (~44 us
// of the 62.5 us total was final+build+gaps per R10 measurement).
// Cross-block visibility: __threadfence + agent-scope atomic (R9-validated).
// ---------------------------------------------------------------------------
__global__ __launch_bounds__(256) void ga_reduce(
    const float* __restrict__ logits,
    const float* __restrict__ sx, const float* __restrict__ sy,
    const float* __restrict__ op, const float* __restrict__ rho,
    float* __restrict__ part, float* __restrict__ MT, int* __restrict__ cnt) {
  __shared__ float s_data[4][64][17];   // 17-pad: conflict-free; reused as s_kern
  __shared__ float s_bin[196];
  __shared__ float s_acc[196];
  __shared__ int   s_m[4];
  __shared__ int   s_ticket;
  const int t    = threadIdx.x;
  const int w    = t >> 6;
  const int lane = t & 63;

  for (int i = t; i < 196; i += 256) s_bin[i] = 0.f;

  const int wid = blockIdx.x * 4 + w;   // 0..3359
  const int cy  = wid / 336;            // class chunk 0..9
  int rem = wid - cy * 336;
  const int b   = rem / 21;             // batch 0..15
  rem -= b * 21;
  const int m   = rem / 3;              // row residue 0..6
  const int kg  = rem - m * 3;          // pair group 0..2
  const int pbase = (4 * m) % 7;        // 2*pbase == m (mod 7)
  if (lane == 0) s_m[w] = m;

  float a[4][4];
#pragma unroll
  for (int k = 0; k < 4; ++k)
#pragma unroll
    for (int e = 0; e < 4; ++e) a[k][e] = 0.f;

  if (lane < 63) {
    const int c0 = cy * CC;
    const float* img = logits + ((size_t)b * NCLS + c0) * NPIX;
#pragma unroll
    for (int r = 0; r < 3; ++r) {
      const int pair = pbase + 7 * (kg * 3 + r);   // y = 2*pair, y%7 == m
      const float4* base =
          reinterpret_cast<const float4*>(img + (size_t)pair * 252) + lane;
      float4 v[CC];
#pragma unroll
      for (int cc = 0; cc < CC; ++cc) v[cc] = base[(size_t)cc * (NPIX / 4)];
#pragma unroll
      for (int cc = 0; cc < CC; ++cc) {
        const int c = c0 + cc;                     // wave-uniform -> s_load
        const float4 vv = v[cc];
        const float p0 = sx[c], p1 = sy[c], p2 = op[c], p3 = rho[c];
        a[0][0] += vv.x * p0; a[0][1] += vv.y * p0; a[0][2] += vv.z * p0; a[0][3] += vv.w * p0;
        a[1][0] += vv.x * p1; a[1][1] += vv.y * p1; a[1][2] += vv.z * p1; a[1][3] += vv.w * p1;
        a[2][0] += vv.x * p2; a[2][1] += vv.y * p2; a[2][2] += vv.z * p2; a[2][3] += vv.w * p2;
        a[3][0] += vv.x * p3; a[3][1] += vv.y * p3; a[3][2] += vv.z * p3; a[3][3] += vv.w * p3;
      }
    }
  }

#pragma unroll
  for (int k = 0; k < 4; ++k) {
    s_data[w][lane][k * 4 + 0] = a[k][0];
    s_data[w][lane][k * 4 + 1] = a[k][1];
    s_data[w][lane][k * 4 + 2] = a[k][2];
    s_data[w][lane][k * 4 + 3] = a[k][3];
  }
  __syncthreads();

  if (t < 224) {                 // (wave, param, row-sel, x-residue) reducers
    const int ww  = t / 56;
    const int r56 = t - ww * 56;
    const int k   = r56 / 14;
    const int rr  = r56 - k * 14;
    const int rs  = rr / 7;      // 0: row y, 1: row y+1
    const int n   = rr - rs * 7; // x % 7
    float s = 0.f;
#pragma unroll
    for (int j = 0; j < 18; ++j) {
      const int f = rs * 126 + n + 7 * j;          // compile-time per (rs,n,j)
      s += s_data[ww][f >> 2][k * 4 + (f & 3)];
    }
    const int mrow = (s_m[ww] + rs) % 7;
    atomicAdd(&s_bin[k * 49 + mrow * 7 + n], s);
  }
  __syncthreads();

  float* my = part + (size_t)blockIdx.x * 196;
  for (int i = t; i < 196; i += 256) my[i] = s_bin[i];

  // ---------------- last-block tail: final reduce + build ----------------
  __threadfence();               // publish partial device-wide
  if (t == 0)
    s_ticket = __hip_atomic_fetch_add(cnt, 1, __ATOMIC_ACQ_REL,
                                      __HIP_MEMORY_SCOPE_AGENT);
  __syncthreads();
  if (s_ticket != NBLK_A - 1) return;

  if (t < 196) {                 // coalesced: thread t owns bin t
    float s0 = 0.f, s1 = 0.f, s2 = 0.f, s3 = 0.f;
    for (int j = 0; j < NBLK_A; j += 4) {
      s0 += part[(size_t)(j + 0) * 196 + t];
      s1 += part[(size_t)(j + 1) * 196 + t];
      s2 += part[(size_t)(j + 2) * 196 + t];
      s3 += part[(size_t)(j + 3) * 196 + t];
    }
    s_acc[t] = (s0 + s1) + (s2 + s3);
  }
  __syncthreads();

  // gaussian build (gb body; s_acc source; s_kern aliases s_data's LDS)
  if (t < 64) {
    float (*s_kern)[49] = reinterpret_cast<float(*)[49]>(&s_data[0][0][0]);
    const int p = t;
    for (int i = p; i < 49; i += 64) {
      MT[i * 52 + 49] = 0.f;
      MT[i * 52 + 50] = 0.f;
      MT[i * 52 + 51] = 0.f;
    }
    if (p < 49) {
      const float inv = 1.0f / 5184.0f;   // mean over BL = 16*18*18
      const float wsx = s_acc[p]        * inv;
      const float wsy = s_acc[49 + p]   * inv;
      const float wop = s_acc[98 + p]   * inv;
      const float wrh = s_acc[147 + p]  * inv;
      const float av = wsx * wsx + 1e-5f;
      const float dv = wsy * wsy + 1e-5f;
      const float bv = wrh * wsx * wsy;
      const float det = av * dv - bv * bv;
      const float norm = 1.0f / (6.283185307179586f * sqrtf(det));
      float tmp[5][5];
      float mx = 0.f;
#pragma unroll
      for (int i = 0; i < 5; ++i) {
        const float gx = -5.0f + 2.5f * (float)i;
#pragma unroll
        for (int j = 0; j < 5; ++j) {
          const float gy = -5.0f + 2.5f * (float)j;
          const float z = -0.5f * (dv*gx*gx - 2.0f*bv*gx*gy + av*gy*gy) / det;
          const float v = expf(z) * norm;
          tmp[i][j] = v;
          mx = fmaxf(mx, v);
        }
      }
      const float rmx = 1.0f / mx;
#pragma unroll
      for (int i = 0; i < 49; ++i) s_kern[p][i] = 0.f;
#pragma unroll
      for (int i = 0; i < 5; ++i)
#pragma unroll
        for (int j = 0; j < 5; ++j)
          s_kern[p][(i + 1) * 7 + (j + 1)] = tmp[i][j] * rmx;

      const int yp = p / 7, xp = p % 7;
      const float tx = (1.0f - (2.0f * (float)xp) / 7.0f) * 3.0f;
      const float ty = (1.0f - (2.0f * (float)yp) / 7.0f) * 3.0f;
      for (int i = 0; i < 7; ++i) {
        const float yq  = (float)i + ty;
        const float y0f = floorf(yq);
        const float fy  = yq - y0f;
        const int   y0  = (int)y0f;
        for (int j = 0; j < 7; ++j) {
          const float xq  = (float)j + tx;
          const float x0f = floorf(xq);
          const float fx  = fy, dummy = 0.f;   // placeholder removed below
          (void)dummy;
          const float fxr = xq - x0f;
          const int   x0  = (int)x0f;
          float v = 0.f;
          for (int dy = 0; dy < 2; ++dy) {
            const int yi = y0 + dy;
            if (yi < 0 || yi > 6) continue;
            const float wy = dy ? fy : (1.0f - fy);
            for (int dx = 0; dx < 2; ++dx) {
              const int xi = x0 + dx;
              if (xi < 0 || xi > 6) continue;
              const float wx = dx ? fxr : (1.0f - fxr);
              v += wy * wx * s_kern[p][yi * 7 + xi];
            }
          }
          MT[(i * 7 + j) * 52 + p] = wop * v;
        }
      }
    }
  }
}

// ---------------------------------------------------------------------------
// Kernel C (R2 body, at its ~3 us floor): one block per (plane, patch-row)
// strip. out[q] = dot49(feat_patch, MT_row[q]); both staged in LDS.
// ---------------------------------------------------------------------------
__global__ __launch_bounds__(256) void gc_splat(
    const float* __restrict__ feat, const float* __restrict__ MT,
    float* __restrict__ out) {
  __shared__ __align__(16) float s_mt[49 * 52];
  __shared__ __align__(16) float s_fp[18 * 52];
  const int t = threadIdx.x;
  for (int i = t; i < 49 * 52; i += 256) s_mt[i] = MT[i];
  const int blk   = blockIdx.x;           // plane*18 + patch_row
  const int plane = blk / 18;
  const int pr    = blk - plane * 18;
  const float* src = feat + (size_t)plane * NPIX + (size_t)pr * 7 * W;
  for (int i = t; i < 882; i += 256) {
    const int py = i / W;
    const int xx = i - py * W;
    const int pc = xx / 7;
    const int px = xx - pc * 7;
    s_fp[pc * 52 + py * 7 + px] = src[i];
  }
  __syncthreads();
  float* dst = out + (size_t)plane * NPIX + (size_t)pr * 7 * W;
  for (int i = t; i < 882; i += 256) {
    const int yy = i / W;
    const int xx = i - yy * W;
    const int pc = xx / 7;
    const int q  = yy * 7 + (xx - pc * 7);
    const float4* mv = reinterpret_cast<const float4*>(s_mt + q * 52);
    const float4* fv = reinterpret_cast<const float4*>(s_fp + pc * 52);
    float s = 0.f;
#pragma unroll
    for (int r = 0; r < 12; ++r) {
      const float4 mm = mv[r];
      const float4 ff = fv[r];
      s += ff.x * mm.x + ff.y * mm.y + ff.z * mm.z + ff.w * mm.w;
    }
    s += s_fp[pc * 52 + 48] * s_mt[q * 52 + 48];
    dst[i] = s;
  }
}

extern "C" void kernel_launch(void* const* d_in, const int* in_sizes, int n_in,
                              void* d_out, int out_size, void* d_ws, size_t ws_size,
                              hipStream_t stream) {
  const float* feat   = (const float*)d_in[0];
  const float* logits = (const float*)d_in[1];
  const float* sx     = (const float*)d_in[2];
  const float* sy     = (const float*)d_in[3];
  const float* op     = (const float*)d_in[4];
  const float* rho    = (const float*)d_in[5];
  float* outp = (float*)d_out;
  float* ws   = (float*)d_ws;
  float* MTp  = ws + WS_MT_OFF;       // 49*52 floats
  int*   cntp = (int*)(ws + WS_CNT_OFF);
  float* partp = ws + WS_PART_OFF;    // 840*196 floats (~658 KB)

  hipMemsetAsync(cntp, 0, 64, stream);   // zero ticket counter each call
  ga_reduce<<<NBLK_A, 256, 0, stream>>>(logits, sx, sy, op, rho,
                                        partp, MTp, cntp);
  gc_splat<<<NB * NCH * 18, 256, 0, stream>>>(feat, MTp, outp);
}

// Round 12
// 72.086 us; speedup vs baseline: 2.5852x; 2.5852x over previous
//
#include <hip/hip_runtime.h>

#define W 126
#define NPIX 15876      // 126*126
#define NB 16
#define NCH 8
#define NCLS 100

#define CC 10           // classes per chunk
#define NPAIR 63        // row pairs (y, y+1), y even
#define NWID (10 * NB * NPAIR)       // 10080 waves
#define NBLK_A (NWID / 4)            // 2520 blocks

// ws layout (floats): acc[0..255], MT[256..], cnt at 3072, partials at 4096..
#define WS_ACC_OFF 0
#define WS_MT_OFF 256
#define WS_CNT_OFF 3072
#define WS_PART_OFF 4096   // TRANSPOSED: part[bin][block], 196 x 2520

// ---------------------------------------------------------------------------
// Kernel A (R6 main body, verbatim — measured 15.5 us): binned contraction
// of logits with (sigma_x, sigma_y, op, rho). Wave = one (class-chunk,
// batch, row-pair). Register accumulation with lane-fixed slots.
// ONLY change: partial write is TRANSPOSED (part[bin*NBLK_A + blk]) so the
// final reduce reads each bin contiguously (R11 showed strided 4B walks
// over cross-XCD lines cost ~2000cy/round; contiguous float4 fixes it).
// ---------------------------------------------------------------------------
__global__ __launch_bounds__(256) void ga_reduce(
    const float* __restrict__ logits,
    const float* __restrict__ sx, const float* __restrict__ sy,
    const float* __restrict__ op, const float* __restrict__ rho,
    float* __restrict__ part) {
  __shared__ float s_data[4][64][17];   // 17-pad: conflict-free
  __shared__ float s_bin[196];
  __shared__ int   s_m[4];
  const int t    = threadIdx.x;
  const int w    = t >> 6;
  const int lane = t & 63;

  for (int i = t; i < 196; i += 256) s_bin[i] = 0.f;

  const int wid  = blockIdx.x * 4 + w;        // 0..10079
  const int cy   = wid / (NB * NPAIR);        // class chunk 0..9
  int rem = wid - cy * (NB * NPAIR);
  const int b    = rem / NPAIR;               // batch 0..15
  const int pair = rem - b * NPAIR;           // row pair 0..62 (y = 2*pair)
  const int m    = (2 * pair) % 7;
  if (lane == 0) s_m[w] = m;

  float a[4][4];
#pragma unroll
  for (int k = 0; k < 4; ++k)
#pragma unroll
    for (int e = 0; e < 4; ++e) a[k][e] = 0.f;

  if (lane < 63) {
    const int c0 = cy * CC;
    const float4* base = reinterpret_cast<const float4*>(
        logits + ((size_t)b * NCLS + c0) * NPIX + (size_t)pair * 252) + lane;

    float4 v[CC];
#pragma unroll
    for (int cc = 0; cc < CC; ++cc) v[cc] = base[(size_t)cc * (NPIX / 4)];

#pragma unroll
    for (int cc = 0; cc < CC; ++cc) {
      const int c = c0 + cc;                  // wave-uniform -> s_load
      const float4 vv = v[cc];
      const float p0 = sx[c], p1 = sy[c], p2 = op[c], p3 = rho[c];
      a[0][0] += vv.x * p0; a[0][1] += vv.y * p0; a[0][2] += vv.z * p0; a[0][3] += vv.w * p0;
      a[1][0] += vv.x * p1; a[1][1] += vv.y * p1; a[1][2] += vv.z * p1; a[1][3] += vv.w * p1;
      a[2][0] += vv.x * p2; a[2][1] += vv.y * p2; a[2][2] += vv.z * p2; a[2][3] += vv.w * p2;
      a[3][0] += vv.x * p3; a[3][1] += vv.y * p3; a[3][2] += vv.z * p3; a[3][3] += vv.w * p3;
    }
  }

#pragma unroll
  for (int k = 0; k < 4; ++k) {
    s_data[w][lane][k * 4 + 0] = a[k][0];
    s_data[w][lane][k * 4 + 1] = a[k][1];
    s_data[w][lane][k * 4 + 2] = a[k][2];
    s_data[w][lane][k * 4 + 3] = a[k][3];
  }
  __syncthreads();

  if (t < 224) {                 // (wave, param, row-sel, x-residue) reducers
    const int ww  = t / 56;
    const int r56 = t - ww * 56;
    const int k   = r56 / 14;
    const int rr  = r56 - k * 14;
    const int rs  = rr / 7;      // 0: row y, 1: row y+1
    const int n   = rr - rs * 7; // x % 7
    float s = 0.f;
#pragma unroll
    for (int j = 0; j < 18; ++j) {
      const int f = rs * 126 + n + 7 * j;     // compile-time per (rs,n,j)
      s += s_data[ww][f >> 2][k * 4 + (f & 3)];
    }
    const int mrow = (s_m[ww] + rs) % 7;
    atomicAdd(&s_bin[k * 49 + mrow * 7 + n], s);
  }
  __syncthreads();

  // transposed partial write: bin-major, contiguous per bin across blocks
  if (t < 196) part[(size_t)t * NBLK_A + blockIdx.x] = s_bin[t];
}

// ---------------------------------------------------------------------------
// Kernel A2+B fused: 49 blocks; wave w reduces bin row (4*blk + w) —
// 2520 contiguous floats = 630 float4, coalesced — then shuffle-reduce,
// lane 0 writes acc[row]. Ticket among the 49 blocks (trivial chain);
// ticket-48 block runs the gaussian build -> MT (R11-validated
// fence->ticket->read visibility pattern).
// ---------------------------------------------------------------------------
__global__ __launch_bounds__(256) void ga_finalbuild(
    const float* __restrict__ part, float* __restrict__ acc,
    float* __restrict__ MT, int* __restrict__ cnt) {
  __shared__ float s_kern[49][49];
  __shared__ float s_acc[196];
  __shared__ int   s_t;
  const int t    = threadIdx.x;
  const int w    = t >> 6;
  const int lane = t & 63;

  const int row = blockIdx.x * 4 + w;       // 0..195
  const float4* src =
      reinterpret_cast<const float4*>(part + (size_t)row * NBLK_A);
  float4 s4 = make_float4(0.f, 0.f, 0.f, 0.f);
  for (int j = lane; j < NBLK_A / 4; j += 64) {   // 630 float4, ~10 rounds
    const float4 v = src[j];
    s4.x += v.x; s4.y += v.y; s4.z += v.z; s4.w += v.w;
  }
  float s = (s4.x + s4.y) + (s4.z + s4.w);
#pragma unroll
  for (int off = 32; off; off >>= 1) s += __shfl_down(s, off);
  if (lane == 0) acc[row] = s;

  __threadfence();               // publish acc row device-wide
  __syncthreads();
  if (t == 0)
    s_t = __hip_atomic_fetch_add(cnt, 1, __ATOMIC_ACQ_REL,
                                 __HIP_MEMORY_SCOPE_AGENT);
  __syncthreads();
  if (s_t != 48) return;

  // ---- last block: gaussian build (gb body, s_acc <- global acc) ----
  if (t < 196) s_acc[t] = acc[t];
  __syncthreads();

  if (t < 64) {
    const int p = t;
    for (int i = p; i < 49; i += 64) {
      MT[i * 52 + 49] = 0.f;
      MT[i * 52 + 50] = 0.f;
      MT[i * 52 + 51] = 0.f;
    }
    if (p < 49) {
      const float inv = 1.0f / 5184.0f;   // mean over BL = 16*18*18
      const float wsx = s_acc[p]        * inv;
      const float wsy = s_acc[49 + p]   * inv;
      const float wop = s_acc[98 + p]   * inv;
      const float wrh = s_acc[147 + p]  * inv;
      const float av = wsx * wsx + 1e-5f;
      const float dv = wsy * wsy + 1e-5f;
      const float bv = wrh * wsx * wsy;
      const float det = av * dv - bv * bv;
      const float norm = 1.0f / (6.283185307179586f * sqrtf(det));
      float tmp[5][5];
      float mx = 0.f;
#pragma unroll
      for (int i = 0; i < 5; ++i) {
        const float gx = -5.0f + 2.5f * (float)i;
#pragma unroll
        for (int j = 0; j < 5; ++j) {
          const float gy = -5.0f + 2.5f * (float)j;
          const float z = -0.5f * (dv*gx*gx - 2.0f*bv*gx*gy + av*gy*gy) / det;
          const float v = expf(z) * norm;
          tmp[i][j] = v;
          mx = fmaxf(mx, v);
        }
      }
      const float rmx = 1.0f / mx;
#pragma unroll
      for (int i = 0; i < 49; ++i) s_kern[p][i] = 0.f;
#pragma unroll
      for (int i = 0; i < 5; ++i)
#pragma unroll
        for (int j = 0; j < 5; ++j)
          s_kern[p][(i + 1) * 7 + (j + 1)] = tmp[i][j] * rmx;

      const int yp = p / 7, xp = p % 7;
      const float tx = (1.0f - (2.0f * (float)xp) / 7.0f) * 3.0f;
      const float ty = (1.0f - (2.0f * (float)yp) / 7.0f) * 3.0f;
      for (int i = 0; i < 7; ++i) {
        const float yq  = (float)i + ty;
        const float y0f = floorf(yq);
        const float fy  = yq - y0f;
        const int   y0  = (int)y0f;
        for (int j = 0; j < 7; ++j) {
          const float xq  = (float)j + tx;
          const float x0f = floorf(xq);
          const float fx  = xq - x0f;
          const int   x0  = (int)x0f;
          float v = 0.f;
          for (int dy = 0; dy < 2; ++dy) {
            const int yi = y0 + dy;
            if (yi < 0 || yi > 6) continue;
            const float wy = dy ? fy : (1.0f - fy);
            for (int dx = 0; dx < 2; ++dx) {
              const int xi = x0 + dx;
              if (xi < 0 || xi > 6) continue;
              const float wx = dx ? fx : (1.0f - fx);
              v += wy * wx * s_kern[p][yi * 7 + xi];
            }
          }
          MT[(i * 7 + j) * 52 + p] = wop * v;
        }
      }
    }
  }
}

// ---------------------------------------------------------------------------
// Kernel C (R2 body, measured ~3 us): one block per (plane, patch-row)
// strip. out[q] = dot49(feat_patch, MT_row[q]); both staged in LDS.
// ---------------------------------------------------------------------------
__global__ __launch_bounds__(256) void gc_splat(
    const float* __restrict__ feat, const float* __restrict__ MT,
    float* __restrict__ out) {
  __shared__ __align__(16) float s_mt[49 * 52];
  __shared__ __align__(16) float s_fp[18 * 52];
  const int t = threadIdx.x;
  for (int i = t; i < 49 * 52; i += 256) s_mt[i] = MT[i];
  const int blk   = blockIdx.x;           // plane*18 + patch_row
  const int plane = blk / 18;
  const int pr    = blk - plane * 18;
  const float* src = feat + (size_t)plane * NPIX + (size_t)pr * 7 * W;
  for (int i = t; i < 882; i += 256) {
    const int py = i / W;
    const int xx = i - py * W;
    const int pc = xx / 7;
    const int px = xx - pc * 7;
    s_fp[pc * 52 + py * 7 + px] = src[i];
  }
  __syncthreads();
  float* dst = out + (size_t)plane * NPIX + (size_t)pr * 7 * W;
  for (int i = t; i < 882; i += 256) {
    const int yy = i / W;
    const int xx = i - yy * W;
    const int pc = xx / 7;
    const int q  = yy * 7 + (xx - pc * 7);
    const float4* mv = reinterpret_cast<const float4*>(s_mt + q * 52);
    const float4* fv = reinterpret_cast<const float4*>(s_fp + pc * 52);
    float s = 0.f;
#pragma unroll
    for (int r = 0; r < 12; ++r) {
      const float4 mm = mv[r];
      const float4 ff = fv[r];
      s += ff.x * mm.x + ff.y * mm.y + ff.z * mm.z + ff.w * mm.w;
    }
    s += s_fp[pc * 52 + 48] * s_mt[q * 52 + 48];
    dst[i] = s;
  }
}

extern "C" void kernel_launch(void* const* d_in, const int* in_sizes, int n_in,
                              void* d_out, int out_size, void* d_ws, size_t ws_size,
                              hipStream_t stream) {
  const float* feat   = (const float*)d_in[0];
  const float* logits = (const float*)d_in[1];
  const float* sx     = (const float*)d_in[2];
  const float* sy     = (const float*)d_in[3];
  const float* op     = (const float*)d_in[4];
  const float* rho    = (const float*)d_in[5];
  float* outp = (float*)d_out;
  float* ws   = (float*)d_ws;
  float* accp = ws + WS_ACC_OFF;      // 196 floats
  float* MTp  = ws + WS_MT_OFF;       // 49*52 floats
  int*   cntp = (int*)(ws + WS_CNT_OFF);
  float* partp = ws + WS_PART_OFF;    // 196 x 2520 floats (~1.97 MB)

  hipMemsetAsync(cntp, 0, 64, stream);   // zero ticket counter each call
  ga_reduce<<<NBLK_A, 256, 0, stream>>>(logits, sx, sy, op, rho, partp);
  ga_finalbuild<<<49, 256, 0, stream>>>(partp, accp, MTp, cntp);
  gc_splat<<<NB * NCH * 18, 256, 0, stream>>>(feat, MTp, outp);
}